// Round 1
// 1108.894 us; speedup vs baseline: 1.1196x; 1.1196x over previous
//
#include <hip/hip_runtime.h>

typedef float v16f __attribute__((ext_vector_type(16)));
typedef int   v8i  __attribute__((ext_vector_type(8)));
typedef int   v4i  __attribute__((ext_vector_type(4)));

#define BM 128
#define BN 128
#define BK 64

// ---------- fp8 pack helper: 4 f32 -> 4 e4m3 bytes (RNE, HW cvt) ----------
__device__ __forceinline__ unsigned int pack4_fp8(float a, float b, float c, float d) {
    unsigned int v = __builtin_amdgcn_cvt_pk_fp8_f32(a, b, 0, false);   // bytes 0,1
    v = __builtin_amdgcn_cvt_pk_fp8_f32(c, d, v, true);                 // bytes 2,3
    return v;
}

// ---------- 1) quantize input: f32 [M,K] -> e4m3 bytes [M,K] ----------
__global__ __launch_bounds__(256) void quant_x_kernel(
    const float* __restrict__ X, const float* __restrict__ sp,
    unsigned int* __restrict__ Q)
{
    const long i = (long)blockIdx.x * 256 + threadIdx.x;
    const float s = sp[0];
    const float4 v = ((const float4*)X)[i];
    const float a = fminf(fmaxf(v.x / s, -448.f), 448.f);
    const float b = fminf(fmaxf(v.y / s, -448.f), 448.f);
    const float c = fminf(fmaxf(v.z / s, -448.f), 448.f);
    const float d = fminf(fmaxf(v.w / s, -448.f), 448.f);
    Q[i] = pack4_fp8(a, b, c, d);
}

// ---------- 2) weight: f32 [K,N] (values already on e4m3 grid) -> e4m3 [N,K] (transposed) ----------
__global__ __launch_bounds__(256) void quant_wT_kernel(
    const float* __restrict__ Wf, unsigned char* __restrict__ Wq, int K, int N)
{
    const int k0 = blockIdx.x * 64;
    const int n0 = blockIdx.y * 64;
    const int t  = threadIdx.x;
    const int n  = t >> 2;          // 0..63
    const int kc = (t & 3) * 16;    // 0,16,32,48
    const float* src = Wf + (long)(k0 + kc) * N + n0 + n;
    unsigned int o[4];
#pragma unroll
    for (int j = 0; j < 4; ++j) {
        const float x0 = src[(long)(4 * j + 0) * N];
        const float x1 = src[(long)(4 * j + 1) * N];
        const float x2 = src[(long)(4 * j + 2) * N];
        const float x3 = src[(long)(4 * j + 3) * N];
        o[j] = pack4_fp8(x0, x1, x2, x3);   // exact: inputs are on the fp8 grid
    }
    uint4 q; q.x = o[0]; q.y = o[1]; q.z = o[2]; q.w = o[3];
    *(uint4*)(Wq + (long)(n0 + n) * K + k0 + kc) = q;
}

// ---------- async 16B global -> LDS ----------
__device__ __forceinline__ void async_copy16(const void* g, void* l) {
    __builtin_amdgcn_global_load_lds(
        (const __attribute__((address_space(1))) unsigned int*)g,
        (__attribute__((address_space(3))) unsigned int*)l,
        16, 0, 0);
}

// ---------- LDS fragment read: 32 B/lane, 16B-slot XOR swizzle ----------
// LDS tile is [128 rows][64 B]; logical chunk c of row r is stored at slot c ^ ((r>>1)&3).
// This spreads the 32-lanes-same-column ds_read_b128 pattern across all 32 banks
// (bank floor for wave64 x 16B); the matching inverse swizzle is applied to the
// GLOBAL source address at staging time (global_load_lds dest must stay linear, rule 21).
__device__ __forceinline__ v8i ld_frag(const unsigned char* base, int row, int c0) {
    const int sw = (row >> 1) & 3;
    const v4i lo = *(const v4i*)(base + row * 64 + (((c0    ) ^ sw) << 4));
    const v4i hi = *(const v4i*)(base + row * 64 + (((c0 + 1) ^ sw) << 4));
    v8i f;
    f[0] = lo[0]; f[1] = lo[1]; f[2] = lo[2]; f[3] = lo[3];
    f[4] = hi[0]; f[5] = hi[1]; f[6] = hi[2]; f[7] = hi[3];
    return f;
}

// ---------- 3) fp8 GEMM via MX-scaled MFMA (unit scales => exact same math) ----------
// C[M,N] = (A8[M,K] . B8[N,K]^T) * s + bias
// 128x128 block tile, BK=64 bytes, 4 waves in 2x2, each wave 64x64 via 2x2 of
// mfma_scale_f32_32x32x64_f8f6f4 (E8M0 scale 0x7F = 1.0; fmt 0 = e4m3).
// vs the non-scaled 16x16x32 fp8 path: 2x K per instruction (5 PF-class pipe rate),
// 8x fewer MFMA instructions, identical LDS/HBM traffic.
// A-fragment: row = l&31, k-run = (l>>5)*32 + i (32 contiguous bytes). B symmetric.
// Any common A/B k-permutation leaves the dot product invariant (unit scales),
// so correctness is robust to the exact within-lane k ordering.
__global__ __launch_bounds__(256) void fp8_gemm_kernel(
    const unsigned char* __restrict__ A8,   // [M,K] e4m3
    const unsigned char* __restrict__ B8,   // [N,K] e4m3 (pre-transposed)
    const float* __restrict__ bias,
    const float* __restrict__ ws_p, const float* __restrict__ is_p,
    float* __restrict__ C, int M, int N, int K)
{
    __shared__ unsigned char AsB[BM * BK];   // 8 KB, [128][64B], slots swizzled
    __shared__ unsigned char BsB[BN * BK];   // 8 KB

    const int tid = threadIdx.x;
    const int l   = tid & 63;
    const int w   = tid >> 6;
    const int wr  = w >> 1, wc = w & 1;     // 2x2 wave grid
    const int lrow = l & 31;                // mfma row/col within 32-tile
    const int c0   = (l >> 5) * 2;          // first 16B chunk of this lane's 32B k-run

    const long m0 = (long)blockIdx.y * BM;
    const long n0 = (long)blockIdx.x * BN;

    // staging: one 16B chunk per lane; source column chunk is inverse-swizzled so the
    // linear global_load_lds write produces LDS[r][s] = G[r][s ^ ((r>>1)&3)].
    // For tid = 4r+s: (tid>>3)&3 == (r>>1)&3 (holds for both 64-row issues).
    const int srow = tid >> 2;
    const int sch  = (tid & 3) ^ ((tid >> 3) & 3);
    const unsigned char* aG = A8 + (m0 + srow) * (long)K + sch * 16;
    const unsigned char* bG = B8 + (n0 + srow) * (long)K + sch * 16;
    const long rowStep = (long)64 * K;

    v16f acc[2][2];
#pragma unroll
    for (int i = 0; i < 2; ++i)
#pragma unroll
        for (int j = 0; j < 2; ++j)
#pragma unroll
            for (int e = 0; e < 16; ++e)
                acc[i][j][e] = 0.f;

    for (int kt = 0; kt < K; kt += BK) {
        async_copy16(aG + kt,           AsB + tid * 16);
        async_copy16(aG + kt + rowStep, AsB + 4096 + tid * 16);
        async_copy16(bG + kt,           BsB + tid * 16);
        async_copy16(bG + kt + rowStep, BsB + 4096 + tid * 16);
        __syncthreads();   // compiler drains vmcnt before s_barrier

        v8i a[2], b[2];
#pragma unroll
        for (int mt = 0; mt < 2; ++mt)
            a[mt] = ld_frag(AsB, wr * 64 + mt * 32 + lrow, c0);
#pragma unroll
        for (int nt = 0; nt < 2; ++nt)
            b[nt] = ld_frag(BsB, wc * 64 + nt * 32 + lrow, c0);

#pragma unroll
        for (int mt = 0; mt < 2; ++mt)
#pragma unroll
            for (int nt = 0; nt < 2; ++nt)
                acc[mt][nt] = __builtin_amdgcn_mfma_scale_f32_32x32x64_f8f6f4(
                    a[mt], b[nt], acc[mt][nt],
                    0 /*cbsz: A=fp8 e4m3*/, 0 /*blgp: B=fp8 e4m3*/,
                    0, 0x7F7F7F7Fu /*scale A = 1.0*/,
                    0, 0x7F7F7F7Fu /*scale B = 1.0*/);
        __syncthreads();
    }

    // epilogue: 32x32 C/D layout: col = l&31, row = (reg&3) + 8*(reg>>2) + 4*(l>>5)
    const float s = is_p[0] * ws_p[0];
#pragma unroll
    for (int mt = 0; mt < 2; ++mt)
#pragma unroll
        for (int nt = 0; nt < 2; ++nt) {
            const long cc = n0 + wc * 64 + nt * 32 + lrow;
            const float bv = bias[cc];
            float* dst = C + (m0 + wr * 64 + mt * 32 + (l >> 5) * 4) * (long)N + cc;
#pragma unroll
            for (int g = 0; g < 4; ++g)
#pragma unroll
                for (int r = 0; r < 4; ++r)
                    dst[(long)(g * 8 + r) * N] = acc[mt][nt][g * 4 + r] * s + bv;
        }
}

extern "C" void kernel_launch(void* const* d_in, const int* in_sizes, int n_in,
                              void* d_out, int out_size, void* d_ws, size_t ws_size,
                              hipStream_t stream)
{
    const float* X    = (const float*)d_in[0];   // [M,K] f32
    const float* Wf   = (const float*)d_in[1];   // [K,N] f32 (fp8-grid values)
    const float* bias = (const float*)d_in[2];   // [N] f32
    const float* wsc  = (const float*)d_in[3];   // weight_scale
    const float* isc  = (const float*)d_in[4];   // input_scale
    float* out = (float*)d_out;

    const int N = in_sizes[2];
    const int K = in_sizes[1] / N;
    const int M = in_sizes[0] / K;

    unsigned char* A8 = (unsigned char*)d_ws;            // M*K bytes
    unsigned char* B8 = A8 + (size_t)M * K;              // N*K bytes

    // 1) input quant: M*K/4 uint words
    quant_x_kernel<<<dim3((unsigned)((long)M * K / 4 / 256)), 256, 0, stream>>>(
        X, isc, (unsigned int*)A8);

    // 2) weight quant + transpose
    quant_wT_kernel<<<dim3(K / 64, N / 64), 256, 0, stream>>>(Wf, B8, K, N);

    // 3) GEMM + scale + bias (MX-scaled fp8, unit scales)
    fp8_gemm_kernel<<<dim3(N / BN, M / BM), 256, 0, stream>>>(
        A8, B8, bias, wsc, isc, out, M, N, K);
}

// Round 2
// 1046.630 us; speedup vs baseline: 1.1862x; 1.0595x over previous
//
#include <hip/hip_runtime.h>

typedef float v16f __attribute__((ext_vector_type(16)));
typedef int   v8i  __attribute__((ext_vector_type(8)));
typedef int   v4i  __attribute__((ext_vector_type(4)));

#define BM 256
#define BN 256
#define BKB 64                      // K-bytes per staged tile
#define NBUF 3
#define TILE_AB 16384               // 256 rows x 64 B (per matrix, per buffer)

// ---------- fp8 pack helper: 4 f32 -> 4 e4m3 bytes (RNE, HW cvt) ----------
__device__ __forceinline__ unsigned int pack4_fp8(float a, float b, float c, float d) {
    unsigned int v = __builtin_amdgcn_cvt_pk_fp8_f32(a, b, 0, false);   // bytes 0,1
    v = __builtin_amdgcn_cvt_pk_fp8_f32(c, d, v, true);                 // bytes 2,3
    return v;
}

// ---------- 1) quantize input: f32 [M,K] -> e4m3 bytes [M,K] ----------
__global__ __launch_bounds__(256) void quant_x_kernel(
    const float* __restrict__ X, const float* __restrict__ sp,
    unsigned int* __restrict__ Q)
{
    const long i = (long)blockIdx.x * 256 + threadIdx.x;
    const float s = sp[0];
    const float4 v = ((const float4*)X)[i];
    const float a = fminf(fmaxf(v.x / s, -448.f), 448.f);
    const float b = fminf(fmaxf(v.y / s, -448.f), 448.f);
    const float c = fminf(fmaxf(v.z / s, -448.f), 448.f);
    const float d = fminf(fmaxf(v.w / s, -448.f), 448.f);
    Q[i] = pack4_fp8(a, b, c, d);
}

// ---------- 2) weight: f32 [K,N] (values already on e4m3 grid) -> e4m3 [N,K] ----------
__global__ __launch_bounds__(256) void quant_wT_kernel(
    const float* __restrict__ Wf, unsigned char* __restrict__ Wq, int K, int N)
{
    const int k0 = blockIdx.x * 64;
    const int n0 = blockIdx.y * 64;
    const int t  = threadIdx.x;
    const int n  = t >> 2;          // 0..63
    const int kc = (t & 3) * 16;    // 0,16,32,48
    const float* src = Wf + (long)(k0 + kc) * N + n0 + n;
    unsigned int o[4];
#pragma unroll
    for (int j = 0; j < 4; ++j) {
        const float x0 = src[(long)(4 * j + 0) * N];
        const float x1 = src[(long)(4 * j + 1) * N];
        const float x2 = src[(long)(4 * j + 2) * N];
        const float x3 = src[(long)(4 * j + 3) * N];
        o[j] = pack4_fp8(x0, x1, x2, x3);   // exact: inputs are on the fp8 grid
    }
    uint4 q; q.x = o[0]; q.y = o[1]; q.z = o[2]; q.w = o[3];
    *(uint4*)(Wq + (long)(n0 + n) * K + k0 + kc) = q;
}

// ---------- async 16B global -> LDS ----------
__device__ __forceinline__ void async_copy16(const void* g, void* l) {
    __builtin_amdgcn_global_load_lds(
        (const __attribute__((address_space(1))) unsigned int*)g,
        (__attribute__((address_space(3))) unsigned int*)l,
        16, 0, 0);
}

// ---------- 3) fp8 GEMM via MX-scaled MFMA, depth-2 counted-vmcnt pipeline ----------
// C[M,N] = (A8[M,K] . B8[N,K]^T) * s + bias
// 256x256 block tile, BK=64 bytes, 512 threads = 8 waves in 2(M)x4(N); each wave owns
// 128x64 = 4x2 tiles of mfma_scale_f32_32x32x64_f8f6f4 (unit E8M0 scales => exact fp8 math).
// Staging pipeline: 3 LDS buffers; iter t issues stage(t+2), then s_waitcnt vmcnt(8)
// (waits ONLY tile t's 4 loads; t+1/t+2's 8 stay in flight across the barrier - T3/T4),
// raw s_barrier (NOT __syncthreads: that would re-insert the vmcnt(0) drain).
// Tail: vmcnt(8) -> vmcnt(4) -> vmcnt(0).
// LDS 16B-slot XOR swizzle (slot = chunk ^ ((row>>1)&3)): applied on the GLOBAL source
// address at stage time (linear global_load_lds dest, rule 21) and on the ds_read side.
// sched_barrier(0) after barrier-1 / before barrier-2 pins ds_reads inside the phase
// (raw s_barrier has no fence semantics; rule 18).
__global__ __launch_bounds__(512, 2) void fp8_gemm_kernel(
    const unsigned char* __restrict__ A8,   // [M,K] e4m3
    const unsigned char* __restrict__ B8,   // [N,K] e4m3 (pre-transposed)
    const float* __restrict__ bias,
    const float* __restrict__ ws_p, const float* __restrict__ is_p,
    float* __restrict__ C, int M, int N, int K)
{
    __shared__ unsigned char AsB[NBUF * TILE_AB];   // 48 KB
    __shared__ unsigned char BsB[NBUF * TILE_AB];   // 48 KB

    const int tid = threadIdx.x;
    const int l   = tid & 63;
    const int w   = tid >> 6;               // 0..7
    const int wr  = w >> 2, wc = w & 3;     // 2(M) x 4(N) wave grid
    const int lrow = l & 31;
    const int c0   = (l >> 5) * 2;          // first 16B chunk of this lane's 32B k-run

    // ---- XCD-aware block swizzle (bijective: grid 43x32 = 1376, %8 == 0) ----
    int bx = blockIdx.x, by = blockIdx.y;
    {
        const int gx = gridDim.x, nwg = gridDim.x * gridDim.y;
        if ((nwg & 7) == 0) {
            const int id  = by * gx + bx;
            const int cpx = nwg >> 3;
            const int swz = (id & 7) * cpx + (id >> 3);
            bx = swz % gx;
            by = swz / gx;
        }
    }
    const long m0 = (long)by * BM;
    const long n0 = (long)bx * BN;

    // ---- staging addresses: 512 threads x 16B = 128 rows x 64B per issue ----
    const int srow = tid >> 2;                              // 0..127
    const int sch  = (tid & 3) ^ ((tid >> 3) & 3);          // inverse slot swizzle
    const unsigned char* aG = A8 + (m0 + srow) * (long)K + sch * 16;
    const unsigned char* bG = B8 + (n0 + srow) * (long)K + sch * 16;
    const long rowStep = (long)128 * K;

    // ---- per-lane LDS fragment byte offsets (both 16B chunks, swizzled) ----
    int offA0[4], offA1[4], offB0[2], offB1[2];
#pragma unroll
    for (int mt = 0; mt < 4; ++mt) {
        const int r  = wr * 128 + mt * 32 + lrow;
        const int sw = (r >> 1) & 3;
        offA0[mt] = r * 64 + (((c0    ) ^ sw) << 4);
        offA1[mt] = r * 64 + (((c0 + 1) ^ sw) << 4);
    }
#pragma unroll
    for (int nt = 0; nt < 2; ++nt) {
        const int r  = wc * 64 + nt * 32 + lrow;
        const int sw = (r >> 1) & 3;
        offB0[nt] = r * 64 + (((c0    ) ^ sw) << 4);
        offB1[nt] = r * 64 + (((c0 + 1) ^ sw) << 4);
    }

    v16f acc[4][2];
#pragma unroll
    for (int i = 0; i < 4; ++i)
#pragma unroll
        for (int j = 0; j < 2; ++j)
#pragma unroll
            for (int e = 0; e < 16; ++e)
                acc[i][j][e] = 0.f;

    const int NT = K / BKB;   // 64

    // ---- stage one 64B K-tile (A+B) into LDS buffer `slot` ----
    auto stage = [&](int ktB, int slot) {
        const unsigned char* ag = aG + ktB;
        const unsigned char* bg = bG + ktB;
        unsigned char* al = AsB + slot * TILE_AB + tid * 16;
        unsigned char* bl = BsB + slot * TILE_AB + tid * 16;
        async_copy16(ag,           al);
        async_copy16(ag + rowStep, al + 8192);
        async_copy16(bg,           bl);
        async_copy16(bg + rowStep, bl + 8192);
    };

    // prologue: tiles 0,1 in flight (8 loads/wave outstanding)
    stage(0, 0);
    stage(BKB, 1);

    int sl_c = 0, sl_p = 2;
    for (int t = 0; t < NT; ++t) {
        if (t + 2 < NT) {
            stage((t + 2) * BKB, sl_p);                       // 12 outstanding
            asm volatile("s_waitcnt vmcnt(8)" ::: "memory");  // tile t done; 8 in flight
        } else if (t + 2 == NT) {
            asm volatile("s_waitcnt vmcnt(4)" ::: "memory");
        } else {
            asm volatile("s_waitcnt vmcnt(0)" ::: "memory");
        }
        __builtin_amdgcn_s_barrier();           // buf[sl_c] ready block-wide
        __builtin_amdgcn_sched_barrier(0);      // no ds_read may hoist above this

        const unsigned char* Ab = AsB + sl_c * TILE_AB;
        const unsigned char* Bb = BsB + sl_c * TILE_AB;
        v8i a[4], b[2];
#pragma unroll
        for (int mt = 0; mt < 4; ++mt) {
            const v4i lo = *(const v4i*)(Ab + offA0[mt]);
            const v4i hi = *(const v4i*)(Ab + offA1[mt]);
            v8i f; f[0]=lo[0]; f[1]=lo[1]; f[2]=lo[2]; f[3]=lo[3];
                   f[4]=hi[0]; f[5]=hi[1]; f[6]=hi[2]; f[7]=hi[3];
            a[mt] = f;
        }
#pragma unroll
        for (int nt = 0; nt < 2; ++nt) {
            const v4i lo = *(const v4i*)(Bb + offB0[nt]);
            const v4i hi = *(const v4i*)(Bb + offB1[nt]);
            v8i f; f[0]=lo[0]; f[1]=lo[1]; f[2]=lo[2]; f[3]=lo[3];
                   f[4]=hi[0]; f[5]=hi[1]; f[6]=hi[2]; f[7]=hi[3];
            b[nt] = f;
        }

        __builtin_amdgcn_s_setprio(1);
#pragma unroll
        for (int mt = 0; mt < 4; ++mt)
#pragma unroll
            for (int nt = 0; nt < 2; ++nt)
                acc[mt][nt] = __builtin_amdgcn_mfma_scale_f32_32x32x64_f8f6f4(
                    a[mt], b[nt], acc[mt][nt],
                    0 /*A=e4m3*/, 0 /*B=e4m3*/,
                    0, 0x7F7F7F7Fu, 0, 0x7F7F7F7Fu /*unit scales*/);
        __builtin_amdgcn_s_setprio(0);

        __builtin_amdgcn_sched_barrier(0);      // reads+MFMA pinned above barrier-2
        __builtin_amdgcn_s_barrier();           // buf[sl_c] free for restage
        sl_c = (sl_c == 2) ? 0 : sl_c + 1;
        sl_p = (sl_p == 2) ? 0 : sl_p + 1;
    }

    // epilogue: 32x32 C/D layout: col = l&31, row = (reg&3) + 8*(reg>>2) + 4*(l>>5)
    const float s = is_p[0] * ws_p[0];
#pragma unroll
    for (int mt = 0; mt < 4; ++mt)
#pragma unroll
        for (int nt = 0; nt < 2; ++nt) {
            const long cc = n0 + wc * 64 + nt * 32 + lrow;
            const float bv = bias[cc];
            float* dst = C + (m0 + wr * 128 + mt * 32 + (l >> 5) * 4) * (long)N + cc;
#pragma unroll
            for (int g = 0; g < 4; ++g)
#pragma unroll
                for (int r = 0; r < 4; ++r)
                    dst[(long)(g * 8 + r) * N] = acc[mt][nt][g * 4 + r] * s + bv;
        }
}

extern "C" void kernel_launch(void* const* d_in, const int* in_sizes, int n_in,
                              void* d_out, int out_size, void* d_ws, size_t ws_size,
                              hipStream_t stream)
{
    const float* X    = (const float*)d_in[0];   // [M,K] f32
    const float* Wf   = (const float*)d_in[1];   // [K,N] f32 (fp8-grid values)
    const float* bias = (const float*)d_in[2];   // [N] f32
    const float* wsc  = (const float*)d_in[3];   // weight_scale
    const float* isc  = (const float*)d_in[4];   // input_scale
    float* out = (float*)d_out;

    const int N = in_sizes[2];
    const int K = in_sizes[1] / N;
    const int M = in_sizes[0] / K;

    unsigned char* A8 = (unsigned char*)d_ws;            // M*K bytes
    unsigned char* B8 = A8 + (size_t)M * K;              // N*K bytes

    // 1) input quant: M*K/4 uint words
    quant_x_kernel<<<dim3((unsigned)((long)M * K / 4 / 256)), 256, 0, stream>>>(
        X, isc, (unsigned int*)A8);

    // 2) weight quant + transpose
    quant_wT_kernel<<<dim3(K / 64, N / 64), 256, 0, stream>>>(Wf, B8, K, N);

    // 3) GEMM + scale + bias (MX-scaled fp8, unit scales, depth-2 pipeline)
    fp8_gemm_kernel<<<dim3(N / BN, M / BM), 512, 0, stream>>>(
        A8, B8, bias, wsc, isc, out, M, N, K);
}